// Round 1
// baseline (1048.607 us; speedup 1.0000x reference)
//
#include <hip/hip_runtime.h>

#define FEAT 1024
#define EPS 1e-5f

typedef float f32x4 __attribute__((ext_vector_type(4)));

// ws layout (floats):
//   [0*F .. 5*F)  : atomic accumulators  sum_r, sum_i, sum_rr, sum_ii, sum_ri
//   [5*F .. 11*F) : fused constants      A_rr, A_ri, A_ir, A_ii, B_r, B_i

// ---------------------------------------------------------------------------
// Kernel 1: per-feature raw-moment sums. Thread t owns features 4t..4t+3.
// 4-row unroll: 8 global loads (128 B/lane) in flight before the first use,
// so the wave drains vmcnt once per 8 KB instead of once per 2 KB.
// Grid 2048 (≈8 blocks/CU requested). 20 atomicAdds per thread at the end.
// ---------------------------------------------------------------------------
__global__ __launch_bounds__(256) void stats_kernel(const float* __restrict__ real,
                                                    const float* __restrict__ imag,
                                                    float* __restrict__ ws,
                                                    int nrows) {
    const int f4 = threadIdx.x * 4;
    float sr[4]  = {0.f, 0.f, 0.f, 0.f};
    float si[4]  = {0.f, 0.f, 0.f, 0.f};
    float srr[4] = {0.f, 0.f, 0.f, 0.f};
    float sii[4] = {0.f, 0.f, 0.f, 0.f};
    float sri[4] = {0.f, 0.f, 0.f, 0.f};

#define ACCUM(RV, IV)                               \
    _Pragma("unroll")                               \
    for (int k = 0; k < 4; ++k) {                   \
        sr[k] += RV[k];                             \
        si[k] += IV[k];                             \
        srr[k] = fmaf(RV[k], RV[k], srr[k]);        \
        sii[k] = fmaf(IV[k], IV[k], sii[k]);        \
        sri[k] = fmaf(RV[k], IV[k], sri[k]);        \
    }

    const int nchunks = nrows >> 2;  // 4-row chunks (nrows = 65536, divisible)
    for (int c = blockIdx.x; c < nchunks; c += gridDim.x) {
        const size_t base = ((size_t)c * 4) * FEAT + f4;
        const f32x4 r0 = *(const f32x4*)(real + base);
        const f32x4 i0 = *(const f32x4*)(imag + base);
        const f32x4 r1 = *(const f32x4*)(real + base + FEAT);
        const f32x4 i1 = *(const f32x4*)(imag + base + FEAT);
        const f32x4 r2 = *(const f32x4*)(real + base + 2 * FEAT);
        const f32x4 i2 = *(const f32x4*)(imag + base + 2 * FEAT);
        const f32x4 r3 = *(const f32x4*)(real + base + 3 * FEAT);
        const f32x4 i3 = *(const f32x4*)(imag + base + 3 * FEAT);
        ACCUM(r0, i0)
        ACCUM(r1, i1)
        ACCUM(r2, i2)
        ACCUM(r3, i3)
    }
#undef ACCUM

#pragma unroll
    for (int k = 0; k < 4; ++k) {
        atomicAdd(&ws[0 * FEAT + f4 + k], sr[k]);
        atomicAdd(&ws[1 * FEAT + f4 + k], si[k]);
        atomicAdd(&ws[2 * FEAT + f4 + k], srr[k]);
        atomicAdd(&ws[3 * FEAT + f4 + k], sii[k]);
        atomicAdd(&ws[4 * FEAT + f4 + k], sri[k]);
    }
}

// ---------------------------------------------------------------------------
// Kernel 2: finalize — one thread per feature. 2x2 inverse-sqrt whitening,
// folds gamma/beta/means into 6 fused constants.
// ---------------------------------------------------------------------------
__global__ __launch_bounds__(256) void finalize_kernel(const float* __restrict__ g_rr_p,
                                                       const float* __restrict__ g_ri_p,
                                                       const float* __restrict__ g_ii_p,
                                                       const float* __restrict__ b_r_p,
                                                       const float* __restrict__ b_i_p,
                                                       float* __restrict__ ws,
                                                       float inv_n) {
    const int f = blockIdx.x * blockDim.x + threadIdx.x;
    if (f >= FEAT) return;

    const float mr = ws[0 * FEAT + f] * inv_n;
    const float mi = ws[1 * FEAT + f] * inv_n;
    const float Crr = ws[2 * FEAT + f] * inv_n - mr * mr + EPS;
    const float Cii = ws[3 * FEAT + f] * inv_n - mi * mi + EPS;
    const float Cri = ws[4 * FEAT + f] * inv_n - mr * mi;

    const float s  = sqrtf(Crr * Cii - Cri * Cri);
    const float tt = sqrtf(Crr + Cii + 2.0f * s);
    const float inv_denom = 1.0f / (s * tt);
    const float Wrr = (Cii + s) * inv_denom;
    const float Wii = (Crr + s) * inv_denom;
    const float Wri = -Cri * inv_denom;

    const float grr = g_rr_p[f], gri = g_ri_p[f], gii = g_ii_p[f];
    const float Arr = grr * Wrr + gri * Wri;
    const float Ari = grr * Wri + gri * Wii;
    const float Air = gri * Wrr + gii * Wri;
    const float Aii = gri * Wri + gii * Wii;
    const float Br  = b_r_p[f] - Arr * mr - Ari * mi;
    const float Bi  = b_i_p[f] - Air * mr - Aii * mi;

    ws[5 * FEAT + f]  = Arr;
    ws[6 * FEAT + f]  = Ari;
    ws[7 * FEAT + f]  = Air;
    ws[8 * FEAT + f]  = Aii;
    ws[9 * FEAT + f]  = Br;
    ws[10 * FEAT + f] = Bi;
}

// ---------------------------------------------------------------------------
// Kernel 3: apply — thread t owns features 4t..4t+3; constants loaded once.
// 2-row unroll (4 loads in flight). REVERSE traversal: stats just finished
// streaming rows ascending, so the highest rows are L3-resident — read them
// first. Non-temporal stores so the 537 MB output stream doesn't evict the
// L3 input lines we are re-reading.
// ---------------------------------------------------------------------------
__global__ __launch_bounds__(256) void apply_kernel(const float* __restrict__ real,
                                                    const float* __restrict__ imag,
                                                    const float* __restrict__ ws,
                                                    float* __restrict__ out,
                                                    int nrows) {
    const int f4 = threadIdx.x * 4;
    const f32x4 Arr = *(const f32x4*)(ws + 5 * FEAT + f4);
    const f32x4 Ari = *(const f32x4*)(ws + 6 * FEAT + f4);
    const f32x4 Air = *(const f32x4*)(ws + 7 * FEAT + f4);
    const f32x4 Aii = *(const f32x4*)(ws + 8 * FEAT + f4);
    const f32x4 Br  = *(const f32x4*)(ws + 9 * FEAT + f4);
    const f32x4 Bi  = *(const f32x4*)(ws + 10 * FEAT + f4);

    float* __restrict__ out_i = out + (size_t)nrows * FEAT;

    const int npairs = nrows >> 1;  // 2-row pairs (nrows = 65536, divisible)
    for (int p = blockIdx.x; p < npairs; p += gridDim.x) {
        const int pr = npairs - 1 - p;  // reverse: L3-warm tail first
        const size_t base = ((size_t)pr * 2) * FEAT + f4;
        const f32x4 r0 = *(const f32x4*)(real + base);
        const f32x4 i0 = *(const f32x4*)(imag + base);
        const f32x4 r1 = *(const f32x4*)(real + base + FEAT);
        const f32x4 i1 = *(const f32x4*)(imag + base + FEAT);

        f32x4 or0, oi0, or1, oi1;
#pragma unroll
        for (int k = 0; k < 4; ++k) {
            or0[k] = fmaf(Arr[k], r0[k], fmaf(Ari[k], i0[k], Br[k]));
            oi0[k] = fmaf(Air[k], r0[k], fmaf(Aii[k], i0[k], Bi[k]));
            or1[k] = fmaf(Arr[k], r1[k], fmaf(Ari[k], i1[k], Br[k]));
            oi1[k] = fmaf(Air[k], r1[k], fmaf(Aii[k], i1[k], Bi[k]));
        }
        __builtin_nontemporal_store(or0, (f32x4*)(out + base));
        __builtin_nontemporal_store(oi0, (f32x4*)(out_i + base));
        __builtin_nontemporal_store(or1, (f32x4*)(out + base + FEAT));
        __builtin_nontemporal_store(oi1, (f32x4*)(out_i + base + FEAT));
    }
}

extern "C" void kernel_launch(void* const* d_in, const int* in_sizes, int n_in,
                              void* d_out, int out_size, void* d_ws, size_t ws_size,
                              hipStream_t stream) {
    const float* real = (const float*)d_in[0];
    const float* imag = (const float*)d_in[1];
    const float* g_rr = (const float*)d_in[2];
    const float* g_ri = (const float*)d_in[3];
    const float* g_ii = (const float*)d_in[4];
    const float* b_r  = (const float*)d_in[5];
    const float* b_i  = (const float*)d_in[6];
    float* out = (float*)d_out;
    float* ws  = (float*)d_ws;

    const int nrows = in_sizes[0] / FEAT;  // 65536

    // Zero the 5*F atomic accumulators (ws is poisoned 0xAA before each call).
    hipMemsetAsync(ws, 0, 5 * FEAT * sizeof(float), stream);

    // Pass 1: stats. 2048 blocks, 4-row chunks, 8 chunks per block.
    stats_kernel<<<2048, 256, 0, stream>>>(real, imag, ws, nrows);

    // Pass 2: finalize 1024 features.
    finalize_kernel<<<4, 256, 0, stream>>>(g_rr, g_ri, g_ii, b_r, b_i, ws,
                                           1.0f / (float)nrows);

    // Pass 3: apply. 2048 blocks, reverse 2-row pairs, NT stores.
    apply_kernel<<<2048, 256, 0, stream>>>(real, imag, ws, out, nrows);
}